// Round 6
// baseline (39683.771 us; speedup 1.0000x reference)
//
#include <hip/hip_runtime.h>
#include <math.h>

#define TSTEPS 256
#define CDIM 171
#define SEQB (TSTEPS*CDIM)

// Fragment-native activation banks: elem offset(col,row) =
// ((col>>3)*128 + row)*8 + (col&7). One MFMA A-fragment load (lane=row,
// quad=k/8) is then contiguous 256B per quad -> coalesced.
#define XP 0              // x bank: 256 cols  (32768 elems)
#define H1B0 32768        // each h bank: 1024 cols (131072 elems)
#define H1B1 163840
#define H2B0 294912
#define H2B1 425984
#define H3B0 557056
#define H3B1 688128
// total X = 819200 elems = 1.6 MB

typedef short v8s __attribute__((ext_vector_type(8)));
typedef float v4f __attribute__((ext_vector_type(4)));

static __device__ __forceinline__ unsigned short f2bf(float f) {
  unsigned int u = __float_as_uint(f);
  u += 0x7fffu + ((u >> 16) & 1u);          // RTNE
  return (unsigned short)(u >> 16);
}
static __device__ __forceinline__ float bf2f(unsigned short h) {
  return __uint_as_float(((unsigned int)h) << 16);
}
static __device__ __forceinline__ float sigf(float x) { return 1.0f / (1.0f + expf(-x)); }

// dtype probe (verified R3/R5): bf16 pairs put a bf16 exponent in bits[14:7]
// of each u32; genuine fp32 puts uniform mantissa bits there.
static __device__ __forceinline__ bool probe_bf16(const unsigned int* w) {
  int c = 0;
  #pragma unroll
  for (int i = 0; i < 8; ++i) {
    unsigned e = (w[i] >> 7) & 0xFFu;
    c += (e >= 90u && e <= 145u) ? 1 : 0;
  }
  return c == 8;
}
static __device__ __forceinline__ float getv(const void* p, bool bf, size_t i) {
  return bf ? bf2f(((const unsigned short*)p)[i]) : ((const float*)p)[i];
}

// ---------------------------------------------------------------------------
// init: seed fragment-native X (t=0 input; zero h banks), bias sums, flags,
// repack ALL weights into K-concatenated canonical bf16 buffers:
//   WL1 [4096][1280] = [wih1 padded to 256 | whh1]
//   WL2/WL3 [4096][2048] = [wih | whh]
//   WDEC [176][1024] = dec_w zero-padded rows
// ---------------------------------------------------------------------------
__global__ __launch_bounds__(256) void init_kernel(
    const void* seq, const void* wih1, const void* whh1,
    const void* bih1, const void* bhh1,
    const void* wih2, const void* whh2, const void* bih2, const void* bhh2,
    const void* wih3, const void* whh3, const void* bih3, const void* bhh3,
    const void* decw,
    unsigned short* __restrict__ X, float* __restrict__ BS,
    unsigned* __restrict__ flags,
    unsigned short* __restrict__ WL1, unsigned short* __restrict__ WL2,
    unsigned short* __restrict__ WL3, unsigned short* __restrict__ WDEC,
    const int* __restrict__ gtp, const int* __restrict__ condp)
{
  const int tid = blockIdx.x * 256 + threadIdx.x;
  const int NT = 2048 * 256;
  const bool bfm = probe_bf16((const unsigned int*)seq);
  int gt = gtp[0];
  const bool p0 = 0 < gt;

  // x bank, fragment-native
  for (int i = tid; i < 32768; i += NT) {
    int grp = i >> 10, rem = i & 1023, row = rem >> 3, e = i & 7;
    int col = grp * 8 + e;
    unsigned short v = 0;
    if (col < CDIM && p0) v = f2bf(getv(seq, bfm, (size_t)row * SEQB + col));
    X[i] = v;
  }
  for (int i = tid; i < 6 * 131072; i += NT) X[32768 + i] = 0;
  const void* bis[3] = {bih1, bih2, bih3};
  const void* bhs[3] = {bhh1, bhh2, bhh3};
  for (int i = tid; i < 3 * 4096; i += NT) {
    int l = i >> 12, n = i & 4095;
    BS[i] = getv(bis[l], bfm, n) + getv(bhs[l], bfm, n);
  }
  for (int i = tid; i < 256; i += NT) flags[i] = 0u;
  for (int i = tid; i < 4096 * 1280; i += NT) {
    int r = i / 1280, c = i - r * 1280;
    float v;
    if (c < CDIM)      v = getv(wih1, bfm, (size_t)r * CDIM + c);
    else if (c < 256)  v = 0.f;
    else               v = getv(whh1, bfm, (size_t)r * 1024 + (c - 256));
    WL1[i] = f2bf(v);
  }
  for (int i = tid; i < 4096 * 2048; i += NT) {
    int r = i >> 11, c = i & 2047;
    size_t o = (size_t)r * 1024 + (c & 1023);
    WL2[i] = f2bf((c < 1024) ? getv(wih2, bfm, o) : getv(whh2, bfm, o));
    WL3[i] = f2bf((c < 1024) ? getv(wih3, bfm, o) : getv(whh3, bfm, o));
  }
  for (int i = tid; i < 176 * 1024; i += NT) {
    int r = i >> 10, c = i & 1023;
    WDEC[i] = (r < CDIM) ? f2bf(getv(decw, bfm, (size_t)r * 1024 + c)) : (unsigned short)0;
  }
}

// ---------------------------------------------------------------------------
// Grid barrier (R5-verified): flag-array + all-poll. __threadfence provides
// the agent-scope L2 writeback (writer) / invalidate (reader) for cross-XCD
// visibility of the plain h stores/loads.
// ---------------------------------------------------------------------------
static __device__ __forceinline__ void gbar(unsigned* fl, int g, unsigned tgt,
                                            int wave, int lane) {
  __syncthreads();
  if (threadIdx.x == 0) {
    __threadfence();
    __hip_atomic_store(fl + g, tgt, __ATOMIC_RELEASE, __HIP_MEMORY_SCOPE_AGENT);
  }
  if (wave == 0) {
    for (;;) {
      unsigned a = __hip_atomic_load(fl + lane,       __ATOMIC_RELAXED, __HIP_MEMORY_SCOPE_AGENT);
      unsigned b = __hip_atomic_load(fl + 64 + lane,  __ATOMIC_RELAXED, __HIP_MEMORY_SCOPE_AGENT);
      unsigned c = __hip_atomic_load(fl + 128 + lane, __ATOMIC_RELAXED, __HIP_MEMORY_SCOPE_AGENT);
      unsigned d = __hip_atomic_load(fl + 192 + lane, __ATOMIC_RELAXED, __HIP_MEMORY_SCOPE_AGENT);
      if (__all((a >= tgt) & (b >= tgt) & (c >= tgt) & (d >= tgt))) break;
      __builtin_amdgcn_s_sleep(1);
    }
    if (lane == 0) __threadfence();
  }
  __syncthreads();
}

// MFMA phase over virtual A = [seg0 | seg1] (split at bnd), fragment-native.
// Xl = X + quad*1024 + l15*8 (lane base). Chunk elem offset =
// ((acol>>3)<<10) + (acol<bnd ? a0base : a1adj); m-tile term = 128*m.
// a1adj = bank1_base - (bnd>>3)*1024 so one formula covers both segments.
template<int NCH>
static __device__ __forceinline__ void mfma_phase(
    const v8s* wf, const unsigned short* __restrict__ Xl,
    int a0base, int bnd, int a1adj, int kbase, v4f* acc)
{
  #pragma unroll
  for (int i = 0; i < 8; ++i) acc[i] = (v4f){0.f, 0.f, 0.f, 0.f};
  #pragma unroll
  for (int c = 0; c < NCH; ++c) {
    const int acol = kbase + 32 * c;              // wave-uniform
    const int off = ((acol >> 3) << 10) + ((acol < bnd) ? a0base : a1adj);
    const unsigned short* ap = Xl + off;
    #pragma unroll
    for (int m = 0; m < 8; ++m) {
      v8s a = *(const v8s*)(ap + (m << 7));
      acc[m] = __builtin_amdgcn_mfma_f32_16x16x32_bf16(a, wf[c], acc[m], 0, 0, 0);
    }
  }
}

// LDS 4-way K-reduce + register-local gate math + bf16 h store.
// LDS row stride 20 floats: quad offsets {0,80,160,240}%32={0,16,0,16} ->
// worst 2-way bank aliasing (free), vs 4-way at stride 16 (R5: 2e8 conflicts).
#define RS 20
#define MS 320              // 16 rows * RS
#define WS 2560             // 8 m-tiles * MS
static __device__ __forceinline__ void lstm_epilogue(
    v4f* acc, float* lred, int wave, int lane,
    const float* bs4, float* cst2,
    unsigned short* __restrict__ X, int hbank, int g)
{
  const int l15 = lane & 15, quad = lane >> 4;
  float* myp = lred + wave * WS;
  #pragma unroll
  for (int m = 0; m < 8; ++m)
    #pragma unroll
    for (int j = 0; j < 4; ++j)
      myp[m * MS + (4 * quad + j) * RS + l15] = acc[m][j];
  __syncthreads();
  const int ri = lane >> 2, hc = lane & 3;
  const int hcol = 4 * g + hc;
  const int hoff = hbank + ((hcol >> 3) << 10) + (hcol & 7);
  #pragma unroll
  for (int e = 0; e < 2; ++e) {
    const int m = 2 * wave + e;
    float z0 = bs4[0], z1 = bs4[1], z2 = bs4[2], z3 = bs4[3];
    #pragma unroll
    for (int w2 = 0; w2 < 4; ++w2) {
      const float* pp = lred + w2 * WS + m * MS + ri * RS + hc;
      z0 += pp[0]; z1 += pp[4]; z2 += pp[8]; z3 += pp[12];
    }
    float cn = sigf(z1) * cst2[e] + sigf(z0) * tanhf(z2);
    float h  = sigf(z3) * tanhf(cn);
    cst2[e] = cn;
    const int row = 32 * wave + 16 * e + ri;
    X[hoff + row * 8] = f2bf(h);
  }
  __syncthreads();   // lred reused next phase
}

// ---------------------------------------------------------------------------
// Persistent kernel (plain launch; co-resident by construction: 40KB LDS,
// 1 WG/CU). WG g owns h-cols [4g,4g+4) of every layer (16 z-cols = 4 hcols
// x 4 gates; B-row for tile col n is 1024*(n>>2)+4g+(n&3)). Waves K-split
// 4-way; weights VGPR-resident; c-state in registers; 4 barriers/step.
// ---------------------------------------------------------------------------
__global__ __launch_bounds__(256, 1) void persist(
    const unsigned short* __restrict__ WL1, const unsigned short* __restrict__ WL2,
    const unsigned short* __restrict__ WL3, const unsigned short* __restrict__ WDEC,
    const float* __restrict__ BS, unsigned short* __restrict__ X,
    unsigned* __restrict__ flags,
    const void* __restrict__ seq, const void* __restrict__ decb,
    void* __restrict__ outp, const int* __restrict__ gtp, const int* __restrict__ condp)
{
  const int g = blockIdx.x;
  const int tid = threadIdx.x, wave = tid >> 6, lane = tid & 63;
  const int l15 = lane & 15, quad = lane >> 4;
  const bool bf = probe_bf16((const unsigned int*)seq);
  int gt = gtp[0]; int per = gt + condp[0]; if (per < 1) per = 1;

  const int br = 1024 * (l15 >> 2) + 4 * g + (l15 & 3);
  v8s w1f[10], w2f[16], w3f[16], wdf[8];
  {
    const unsigned short* p = WL1 + (size_t)br * 1280 + 320 * wave + 8 * quad;
    #pragma unroll
    for (int c = 0; c < 10; ++c) w1f[c] = *(const v8s*)(p + 32 * c);
  }
  {
    const unsigned short* p = WL2 + (size_t)br * 2048 + 512 * wave + 8 * quad;
    #pragma unroll
    for (int c = 0; c < 16; ++c) w2f[c] = *(const v8s*)(p + 32 * c);
  }
  {
    const unsigned short* p = WL3 + (size_t)br * 2048 + 512 * wave + 8 * quad;
    #pragma unroll
    for (int c = 0; c < 16; ++c) w3f[c] = *(const v8s*)(p + 32 * c);
  }
  const int dm = g / 11, dn = g - dm * 11;
  if (g < 88) {
    const unsigned short* p = WDEC + (size_t)(16 * dn + l15) * 1024 + 256 * wave + 8 * quad;
    #pragma unroll
    for (int c = 0; c < 8; ++c) wdf[c] = *(const v8s*)(p + 32 * c);
  } else {
    #pragma unroll
    for (int c = 0; c < 8; ++c) wdf[c] = (v8s){0, 0, 0, 0, 0, 0, 0, 0};
  }
  float bsr[3][4];
  #pragma unroll
  for (int l = 0; l < 3; ++l)
    #pragma unroll
    for (int gm = 0; gm < 4; ++gm)
      bsr[l][gm] = BS[4096 * l + 1024 * gm + 4 * g + (lane & 3)];
  float dbv = 0.f;
  if (g < 88) { int col = 16 * dn + l15; if (col < CDIM) dbv = getv(decb, bf, col); }

  float cst1[2] = {0.f, 0.f}, cst2v[2] = {0.f, 0.f}, cst3[2] = {0.f, 0.f};
  __shared__ float lred[10240];                     // 4 waves * WS, rs=20 padded
  const unsigned short* Xl = X + quad * 1024 + l15 * 8;  // lane A-base
  unsigned bgen = 0;
  v4f acc[8];
  const int H1B[2] = {H1B0, H1B1}, H2B[2] = {H2B0, H2B1}, H3B[2] = {H3B0, H3B1};

  for (int t = 0; t < TSTEPS; ++t) {
    const int p_ = t & 1, q_ = p_ ^ 1;
    gbar(flags, g, ++bgen, wave, lane);              // dec(t-1) -> L1(t)
    // L1: A = [x(256) | h1(q)]
    mfma_phase<10>(w1f, Xl, XP, 256, H1B[q_] - 32768, 320 * wave, acc);
    lstm_epilogue(acc, lred, wave, lane, bsr[0], cst1, X, H1B[p_], g);
    gbar(flags, g, ++bgen, wave, lane);
    // L2: A = [h1(p) | h2(q)]
    mfma_phase<16>(w2f, Xl, H1B[p_], 1024, H2B[q_] - 131072, 512 * wave, acc);
    lstm_epilogue(acc, lred, wave, lane, bsr[1], cst2v, X, H2B[p_], g);
    gbar(flags, g, ++bgen, wave, lane);
    // L3: A = [h2(p) | h3(q)]
    mfma_phase<16>(w3f, Xl, H2B[p_], 1024, H3B[q_] - 131072, 512 * wave, acc);
    lstm_epilogue(acc, lred, wave, lane, bsr[2], cst3, X, H3B[p_], g);
    gbar(flags, g, ++bgen, wave, lane);              // L3 -> dec
    if (g < 88) {
      v4f da = (v4f){0.f, 0.f, 0.f, 0.f};
      const int rowb = (16 * dm + l15) * 8;
      #pragma unroll
      for (int c = 0; c < 8; ++c) {
        const int grp = 32 * wave + 4 * c + quad;
        v8s a = *(const v8s*)(X + H3B[p_] + (grp << 10) + rowb);
        da = __builtin_amdgcn_mfma_f32_16x16x32_bf16(a, wdf[c], da, 0, 0, 0);
      }
      float* myp = lred + wave * WS;
      #pragma unroll
      for (int j = 0; j < 4; ++j) myp[(4 * quad + j) * RS + l15] = da[j];
      __syncthreads();
      if (wave == 0) {
        const int col = 16 * dn + l15;
        const bool pnext = ((t + 1) % per) < gt;
        #pragma unroll
        for (int e = 0; e < 4; ++e) {
          const int r = 4 * e + quad;
          float v = dbv;
          #pragma unroll
          for (int w2 = 0; w2 < 4; ++w2) v += lred[w2 * WS + r * RS + l15];
          if (col < CDIM) {
            const int brow = 16 * dm + r;
            const size_t oidx = (size_t)brow * SEQB + (size_t)t * CDIM + col;
            if (bf) ((unsigned short*)outp)[oidx] = f2bf(v);
            else    ((float*)outp)[oidx] = v;
            if (t < TSTEPS - 1) {
              float xn = pnext ? getv(seq, bf, (size_t)brow * SEQB + (size_t)(t + 1) * CDIM + col)
                               : v;
              X[XP + ((col >> 3) << 10) + brow * 8 + (col & 7)] = f2bf(xn);
            }
          }
        }
      }
    }
  }
}

// ---------------------------------------------------------------------------
// Workspace (bytes, total ~46.1 MB):
//   X     @ 0         : 819200 bf16 elems, fragment-native banks
//   BS    @ 1638400   : [3][4096] fp32
//   FLAGS @ 1687552   : [256] u32 barrier flags
//   WL1   @ 1690624   : [4096][1280] bf16
//   WL2   @ 12176384  : [4096][2048] bf16
//   WL3   @ 28953600  : [4096][2048] bf16
//   WDEC  @ 45730816  : [176][1024] bf16
// ---------------------------------------------------------------------------
extern "C" void kernel_launch(void* const* d_in, const int* in_sizes, int n_in,
                              void* d_out, int out_size, void* d_ws, size_t ws_size,
                              hipStream_t stream) {
  const void* seq  = d_in[0];
  const void* wih1 = d_in[1];  const void* whh1 = d_in[2];
  const void* bih1 = d_in[3];  const void* bhh1 = d_in[4];
  const void* wih2 = d_in[5];  const void* whh2 = d_in[6];
  const void* bih2 = d_in[7];  const void* bhh2 = d_in[8];
  const void* wih3 = d_in[9];  const void* whh3 = d_in[10];
  const void* bih3 = d_in[11]; const void* bhh3 = d_in[12];
  const void* decw = d_in[13]; const void* decb = d_in[14];
  const int* gtp   = (const int*)d_in[15];
  const int* condp = (const int*)d_in[16];

  char* ws = (char*)d_ws;
  unsigned short* X    = (unsigned short*)(ws + 0);
  float*          BS   = (float*)(ws + 1638400);
  unsigned*       FLAGS= (unsigned*)(ws + 1687552);
  unsigned short* WL1  = (unsigned short*)(ws + 1690624);
  unsigned short* WL2  = (unsigned short*)(ws + 12176384);
  unsigned short* WL3  = (unsigned short*)(ws + 28953600);
  unsigned short* WDEC = (unsigned short*)(ws + 45730816);

  init_kernel<<<2048, 256, 0, stream>>>(seq, wih1, whh1, bih1, bhh1,
                                        wih2, whh2, bih2, bhh2,
                                        wih3, whh3, bih3, bhh3, decw,
                                        X, BS, FLAGS, WL1, WL2, WL3, WDEC,
                                        gtp, condp);

  persist<<<256, 256, 0, stream>>>(WL1, WL2, WL3, WDEC, BS, X, FLAGS,
                                   seq, decb, d_out, gtp, condp);
}